// Round 1
// baseline (156.429 us; speedup 1.0000x reference)
//
#include <hip/hip_runtime.h>
#include <hip/hip_bf16.h>

// CriticREM: out = relu(relu([state|action]W1^T+b1)W2^T+b2) @ Wc^T + bc
//   Wc = sum_h alpha_h * Wh[h], bc = sum_h alpha_h * bh[h]
// B=65536, IN=128, HID=256, NUM_HEADS=200, OUT=1
//
// R8: ELIMINATE WORKSPACE — fuse prep into the main kernel.
//   Evidence (R7 rocprof): top-5 dispatches are all 256 MiB
//   fillBufferAligned (44-46 us each, 73-75% HBM peak); critic_kernel is
//   below all of them (<44 us). dur_us=112 ~= 2x45 (ws poison fills) +
//   prep + ~17 us kernel. Theory: the harness re-poisons d_ws inside the
//   timed window because we use it. Fix: never touch d_ws.
//     - W1/W2 MFMA fragments: load fp32 straight from inputs in the
//       preamble, convert to bf16 in-register (weights are L2-resident:
//       590 KB total, 256 blocks re-read -> L2 hits).
//     - Head collapse (Wc, bc): each lane accumulates its own 8 Wc
//       entries over 200 heads in fp32, same h-order as prep -> identical
//       numerics. alphas[h]/bh[h] are wave-uniform -> s_load.
//   Main GEMM loop byte-identical to R7 to isolate the variable.

#define B_TOTAL 65536
#define SDIM 96
#define ADIM 32
#define IN_F 128
#define HID 256
#define NHEADS 200
#define BM 64           // batch rows per tile
#define NTILES 4        // tiles per block (grid 256)
#define XS_PITCH 132    // 264B row stride = 66 dw == 2 mod 32: conflict-free class
#define H1_PITCH 260    // 520B row stride = 130 dw == 2 mod 32: measured 0 (R2)

typedef __bf16 bf16;
typedef __attribute__((ext_vector_type(4))) __bf16 bf16x4;
typedef __attribute__((ext_vector_type(8))) __bf16 bf16x8;
typedef __attribute__((ext_vector_type(4))) float f32x4;

// ---- single fused kernel: 512 threads (8 waves), persistent over 4 tiles ----
__global__ __launch_bounds__(512, 2) void critic_kernel(
        const float* __restrict__ state, const float* __restrict__ action,
        const float* __restrict__ alphas,
        const float* __restrict__ W1, const float* __restrict__ b1,
        const float* __restrict__ W2, const float* __restrict__ b2,
        const float* __restrict__ Wh, const float* __restrict__ bh,
        float* __restrict__ out) {

    __shared__ bf16 xs[BM * XS_PITCH];     // 16896 B, x tile [batch][k]
    __shared__ bf16 h1s[BM * H1_PITCH];    // 33280 B, h1 tile [batch][hidden]
    __shared__ float sPart[8][BM];         // 2048 B

    const int tid  = threadIdx.x;
    const int wave = tid >> 6;      // 0..7
    const int lane = tid & 63;
    const int q    = lane >> 4;     // 0..3
    const int ln   = lane & 15;     // 0..15
    const int colw = wave * 32;     // this wave's 32-hidden-col slice
    const int brow0 = blockIdx.x * (BM * NTILES);

    // ---- x prefetch for tile 0 FIRST: HBM stream, longest latency ----
    float4 px[2][2];
    #pragma unroll
    for (int i = 0; i < 2; ++i) {
        const int c  = tid + i * 512;
        const int r  = c >> 4;
        const int c8 = c & 15;
        const float* src = (c8 < 12) ? (state  + (size_t)(brow0 + r) * SDIM + c8 * 8)
                                     : (action + (size_t)(brow0 + r) * ADIM + (c8 - 12) * 8);
        px[i][0] = ((const float4*)src)[0];
        px[i][1] = ((const float4*)src)[1];
    }

    // ---- preamble: ALL weight fragments into registers, once per block ----
    // A-operand layout: A[m'=ln][k=q*8+j]; fp32 source, convert in-register.
    bf16x8 w1f[4][2];   // 32 VGPR : W1[colw+nt*16+ln][ks*32+q*8 ..]
    #pragma unroll
    for (int ks = 0; ks < 4; ++ks)
        #pragma unroll
        for (int nt = 0; nt < 2; ++nt) {
            const float* p = &W1[(size_t)(colw + nt * 16 + ln) * IN_F + ks * 32 + q * 8];
            float4 lo = ((const float4*)p)[0];
            float4 hi = ((const float4*)p)[1];
            w1f[ks][nt] = (bf16x8){(bf16)lo.x, (bf16)lo.y, (bf16)lo.z, (bf16)lo.w,
                                   (bf16)hi.x, (bf16)hi.y, (bf16)hi.z, (bf16)hi.w};
        }

    bf16x8 w2f[8][2];   // 64 VGPR
    #pragma unroll
    for (int ks = 0; ks < 8; ++ks)
        #pragma unroll
        for (int nt = 0; nt < 2; ++nt) {
            const float* p = &W2[(size_t)(colw + nt * 16 + ln) * HID + ks * 32 + q * 8];
            float4 lo = ((const float4*)p)[0];
            float4 hi = ((const float4*)p)[1];
            w2f[ks][nt] = (bf16x8){(bf16)lo.x, (bf16)lo.y, (bf16)lo.z, (bf16)lo.w,
                                   (bf16)hi.x, (bf16)hi.y, (bf16)hi.z, (bf16)hi.w};
        }

    // epilogue constants: hidden col n = colw + nt*16 + q*4 + r -> float4 loads
    f32x4 b1v[2], b2v[2], wcv[2];
    #pragma unroll
    for (int nt = 0; nt < 2; ++nt) {
        const int n4 = colw + nt * 16 + q * 4;
        b1v[nt] = *(const f32x4*)&b1[n4];
        b2v[nt] = *(const f32x4*)&b2[n4];
        wcv[nt] = (f32x4){0.f, 0.f, 0.f, 0.f};
    }
    // head collapse in-lane: wcv[nt][r] = sum_h alphas[h]*Wh[h][colw+nt*16+q*4+r]
    float bc = 0.f;
    {
        const int n4 = colw + q * 4;
        #pragma unroll 8
        for (int h = 0; h < NHEADS; ++h) {
            const float al = alphas[h];
            const float* wh = Wh + (size_t)h * HID;
            const f32x4 v0 = *(const f32x4*)&wh[n4];
            const f32x4 v1 = *(const f32x4*)&wh[n4 + 16];
            #pragma unroll
            for (int r = 0; r < 4; ++r) {
                wcv[0][r] += al * v0[r];
                wcv[1][r] += al * v1[r];
            }
            bc += al * bh[h];
        }
    }

    for (int t = 0; t < NTILES; ++t) {
        const int row0 = brow0 + t * BM;

        // stage x tile: fp32 -> bf16 into LDS [batch][k]
        #pragma unroll
        for (int i = 0; i < 2; ++i) {
            const int c  = tid + i * 512;
            const int r  = c >> 4;
            const int c8 = c & 15;
            bf16x8 v = (bf16x8){(bf16)px[i][0].x, (bf16)px[i][0].y, (bf16)px[i][0].z, (bf16)px[i][0].w,
                                (bf16)px[i][1].x, (bf16)px[i][1].y, (bf16)px[i][1].z, (bf16)px[i][1].w};
            *(bf16x8*)&xs[r * XS_PITCH + c8 * 8] = v;
        }
        __syncthreads();

        // prefetch NEXT tile's x while this tile computes
        if (t + 1 < NTILES) {
            const int nrow0 = row0 + BM;
            #pragma unroll
            for (int i = 0; i < 2; ++i) {
                const int c  = tid + i * 512;
                const int r  = c >> 4;
                const int c8 = c & 15;
                const float* src = (c8 < 12) ? (state  + (size_t)(nrow0 + r) * SDIM + c8 * 8)
                                             : (action + (size_t)(nrow0 + r) * ADIM + (c8 - 12) * 8);
                px[i][0] = ((const float4*)src)[0];
                px[i][1] = ((const float4*)src)[1];
            }
        }

        // ---- GEMM1 (transposed): D1[n][m] = W1 . x^T over this wave's 32 n ----
        // A = w1f (regs), B = xs rows: B[k=q*8+j][m'=ln] = x[mt*16+ln][ks*32+q*8+j]
        f32x4 acc[4][2];   // [mt][nt]
        #pragma unroll
        for (int mt = 0; mt < 4; ++mt)
            #pragma unroll
            for (int nt = 0; nt < 2; ++nt)
                acc[mt][nt] = (f32x4){0.f, 0.f, 0.f, 0.f};

        #pragma unroll
        for (int ks = 0; ks < 4; ++ks) {
            const int k0 = ks * 32 + q * 8;
            bf16x8 bfr[4];
            #pragma unroll
            for (int mt = 0; mt < 4; ++mt)
                bfr[mt] = *(const bf16x8*)&xs[(mt * 16 + ln) * XS_PITCH + k0];
            #pragma unroll
            for (int mt = 0; mt < 4; ++mt)
                #pragma unroll
                for (int nt = 0; nt < 2; ++nt)
                    acc[mt][nt] = __builtin_amdgcn_mfma_f32_16x16x32_bf16(w1f[ks][nt], bfr[mt], acc[mt][nt], 0, 0, 0);
        }

        // epi1: bias+relu; regs r=0..3 are 4 CONSECUTIVE hidden cols at batch
        // row mt*16+ln -> one ds_write_b64 per (nt,mt)
        #pragma unroll
        for (int nt = 0; nt < 2; ++nt) {
            #pragma unroll
            for (int mt = 0; mt < 4; ++mt) {
                bf16x4 v4;
                #pragma unroll
                for (int r = 0; r < 4; ++r) {
                    float v = acc[mt][nt][r] + b1v[nt][r];
                    v = v > 0.f ? v : 0.f;
                    v4[r] = (bf16)v;
                }
                *(bf16x4*)&h1s[(mt * 16 + ln) * H1_PITCH + colw + nt * 16 + q * 4] = v4;
            }
        }
        __syncthreads();

        // ---- GEMM2 (transposed): D2[n][m] = W2 . h1^T ----
        #pragma unroll
        for (int mt = 0; mt < 4; ++mt)
            #pragma unroll
            for (int nt = 0; nt < 2; ++nt)
                acc[mt][nt] = (f32x4){0.f, 0.f, 0.f, 0.f};

        #pragma unroll
        for (int ks = 0; ks < 8; ++ks) {
            const int k0 = ks * 32 + q * 8;
            bf16x8 bfr[4];
            #pragma unroll
            for (int mt = 0; mt < 4; ++mt)
                bfr[mt] = *(const bf16x8*)&h1s[(mt * 16 + ln) * H1_PITCH + k0];
            #pragma unroll
            for (int mt = 0; mt < 4; ++mt)
                #pragma unroll
                for (int nt = 0; nt < 2; ++nt)
                    acc[mt][nt] = __builtin_amdgcn_mfma_f32_16x16x32_bf16(w2f[ks][nt], bfr[mt], acc[mt][nt], 0, 0, 0);
        }

        // epi2: bias+relu+Wc-dot IN-LANE over (nt,r); per-lane partial[mt] is
        // the contribution of hidden cols {colw+nt*16+q*4+r} to batch row
        // mt*16+ln. Cross-lane reduce only over q: shfl_xor 16,32.
        float partial[4];
        #pragma unroll
        for (int mt = 0; mt < 4; ++mt) {
            float p = 0.f;
            #pragma unroll
            for (int nt = 0; nt < 2; ++nt)
                #pragma unroll
                for (int r = 0; r < 4; ++r) {
                    float v = acc[mt][nt][r] + b2v[nt][r];
                    v = v > 0.f ? v : 0.f;
                    p += v * wcv[nt][r];
                }
            partial[mt] = p;
        }
        #pragma unroll
        for (int mt = 0; mt < 4; ++mt) {
            partial[mt] += __shfl_xor(partial[mt], 16, 64);
            partial[mt] += __shfl_xor(partial[mt], 32, 64);
        }
        if (q == 0) {
            #pragma unroll
            for (int mt = 0; mt < 4; ++mt)
                sPart[wave][mt * 16 + ln] = partial[mt];
        }
        __syncthreads();

        if (tid < BM) {
            float v = bc;
            #pragma unroll
            for (int w = 0; w < 8; ++w) v += sPart[w][tid];
            out[row0 + tid] = v;
        }
        // barrier above also orders next tile's xs writes after this tile's reads
    }
}

extern "C" void kernel_launch(void* const* d_in, const int* in_sizes, int n_in,
                              void* d_out, int out_size, void* d_ws, size_t ws_size,
                              hipStream_t stream) {
    const float* state  = (const float*)d_in[0];
    const float* action = (const float*)d_in[1];
    const float* alphas = (const float*)d_in[2];
    const float* W1     = (const float*)d_in[3];
    const float* b1     = (const float*)d_in[4];
    const float* W2     = (const float*)d_in[5];
    const float* b2     = (const float*)d_in[6];
    const float* Wh     = (const float*)d_in[7];
    const float* bh     = (const float*)d_in[8];
    float* out = (float*)d_out;

    // d_ws deliberately UNUSED (R8): workspace poison fills dominated dur_us.
    (void)d_ws; (void)ws_size;

    critic_kernel<<<B_TOTAL / (BM * NTILES), 512, 0, stream>>>(
        state, action, alphas, W1, b1, W2, b2, Wh, bh, out);
}

// Round 2
// 147.606 us; speedup vs baseline: 1.0598x; 1.0598x over previous
//
#include <hip/hip_runtime.h>
#include <hip/hip_bf16.h>

// CriticREM: out = relu(relu([state|action]W1^T+b1)W2^T+b2) @ Wc^T + bc
//   Wc = sum_h alpha_h * Wh[h], bc = sum_h alpha_h * bh[h]
// B=65536, IN=128, HID=256, NUM_HEADS=200, OUT=1
//
// R9: back to ws prep + 2 BLOCKS PER CU.
//   R8 evidence: the 256 MiB fill is UNCONDITIONAL (avoiding d_ws saved
//   nothing; total went UP because the fused preamble added ~55 us of
//   serial, 16x-redundant head-collapse work to every block). So ws is
//   free -> prep_kernel returns. Critic counters (first time visible):
//   VGPR=128 chosen freely (no spill pressure), Occupancy 22% == one
//   8-wave block per CU -> occupancy is GRID-limited. All pipes idle
//   (Mfma 5%, VALU 10%, HBM 2.5%): latency/barrier-bound convoy.
//   Fix: grid 512, NTILES=2, __launch_bounds__(512,4) -> 2 blocks/CU
//   (LDS 2x52KB=104KB ok, VGPR 128 -> 16 waves/CU). Two independent
//   barrier groups per CU overlap each other's stalls.
//   Main GEMM loop byte-identical to R7/R8.

#define B_TOTAL 65536
#define SDIM 96
#define ADIM 32
#define IN_F 128
#define HID 256
#define NHEADS 200
#define BM 64           // batch rows per tile
#define NTILES 2        // tiles per block (grid 512 -> 2 blocks/CU)
#define XS_PITCH 132    // 264B row stride = 66 dw == 2 mod 32: conflict-free class
#define H1_PITCH 260    // 520B row stride = 130 dw == 2 mod 32: measured 0 (R2)

typedef __bf16 bf16;
typedef __attribute__((ext_vector_type(4))) __bf16 bf16x4;
typedef __attribute__((ext_vector_type(8))) __bf16 bf16x8;
typedef __attribute__((ext_vector_type(4))) float f32x4;

// ---- prep: W1,W2 -> bf16 in ws; collapse heads: Wc[256], bc (fp32) ----
__global__ void prep_kernel(const float* __restrict__ W1, const float* __restrict__ W2,
                            const float* __restrict__ alphas, const float* __restrict__ Wh,
                            const float* __restrict__ bh,
                            bf16* __restrict__ W1bf, bf16* __restrict__ W2bf,
                            float* __restrict__ Wc) {
    int tid = blockIdx.x * blockDim.x + threadIdx.x;
    if (tid < IN_F * HID) W1bf[tid] = (bf16)W1[tid];
    if (tid < HID * HID)  W2bf[tid] = (bf16)W2[tid];
    if (tid < HID) {
        float acc = 0.f;
        #pragma unroll 8
        for (int h = 0; h < NHEADS; ++h) acc += alphas[h] * Wh[h * HID + tid];
        Wc[tid] = acc;
    }
    if (tid == HID) {
        float acc = 0.f;
        for (int h = 0; h < NHEADS; ++h) acc += alphas[h] * bh[h];
        Wc[HID] = acc;   // bc
    }
}

// ---- main fused kernel: 512 threads (8 waves), 2 tiles, 2 blocks/CU ----
__global__ __launch_bounds__(512, 4) void critic_kernel(
        const float* __restrict__ state, const float* __restrict__ action,
        const float* __restrict__ b1, const float* __restrict__ b2,
        const bf16* __restrict__ W1bf, const bf16* __restrict__ W2bf,
        const float* __restrict__ Wc, float* __restrict__ out) {

    __shared__ bf16 xs[BM * XS_PITCH];     // 16896 B, x tile [batch][k]
    __shared__ bf16 h1s[BM * H1_PITCH];    // 33280 B, h1 tile [batch][hidden]
    __shared__ float sPart[8][BM];         // 2048 B

    const int tid  = threadIdx.x;
    const int wave = tid >> 6;      // 0..7
    const int lane = tid & 63;
    const int q    = lane >> 4;     // 0..3
    const int ln   = lane & 15;     // 0..15
    const int colw = wave * 32;     // this wave's 32-hidden-col slice
    const int brow0 = blockIdx.x * (BM * NTILES);

    // ---- x prefetch for tile 0 FIRST: HBM stream, longest latency ----
    float4 px[2][2];
    #pragma unroll
    for (int i = 0; i < 2; ++i) {
        const int c  = tid + i * 512;
        const int r  = c >> 4;
        const int c8 = c & 15;
        const float* src = (c8 < 12) ? (state  + (size_t)(brow0 + r) * SDIM + c8 * 8)
                                     : (action + (size_t)(brow0 + r) * ADIM + (c8 - 12) * 8);
        px[i][0] = ((const float4*)src)[0];
        px[i][1] = ((const float4*)src)[1];
    }

    // ---- preamble: ALL weight fragments into registers, once per block ----
    // A-operand layout: A[m'=ln][k=q*8+j] -> same data we always loaded.
    bf16x8 w1f[4][2];   // 32 VGPR : W1[colw+nt*16+ln][ks*32+q*8 ..]
    #pragma unroll
    for (int ks = 0; ks < 4; ++ks)
        #pragma unroll
        for (int nt = 0; nt < 2; ++nt)
            w1f[ks][nt] = *(const bf16x8*)&W1bf[(size_t)(colw + nt * 16 + ln) * IN_F + ks * 32 + q * 8];

    bf16x8 w2f[8][2];   // 64 VGPR
    #pragma unroll
    for (int ks = 0; ks < 8; ++ks)
        #pragma unroll
        for (int nt = 0; nt < 2; ++nt)
            w2f[ks][nt] = *(const bf16x8*)&W2bf[(size_t)(colw + nt * 16 + ln) * HID + ks * 32 + q * 8];

    // epilogue constants: hidden col n = colw + nt*16 + q*4 + r  -> float4 loads
    f32x4 b1v[2], b2v[2], wcv[2];
    #pragma unroll
    for (int nt = 0; nt < 2; ++nt) {
        const int n4 = colw + nt * 16 + q * 4;
        b1v[nt] = *(const f32x4*)&b1[n4];
        b2v[nt] = *(const f32x4*)&b2[n4];
        wcv[nt] = *(const f32x4*)&Wc[n4];
    }
    const float bc = Wc[HID];

    for (int t = 0; t < NTILES; ++t) {
        const int row0 = brow0 + t * BM;

        // stage x tile: fp32 -> bf16 into LDS [batch][k]
        #pragma unroll
        for (int i = 0; i < 2; ++i) {
            const int c  = tid + i * 512;
            const int r  = c >> 4;
            const int c8 = c & 15;
            bf16x8 v = (bf16x8){(bf16)px[i][0].x, (bf16)px[i][0].y, (bf16)px[i][0].z, (bf16)px[i][0].w,
                                (bf16)px[i][1].x, (bf16)px[i][1].y, (bf16)px[i][1].z, (bf16)px[i][1].w};
            *(bf16x8*)&xs[r * XS_PITCH + c8 * 8] = v;
        }
        __syncthreads();

        // prefetch NEXT tile's x while this tile computes
        if (t + 1 < NTILES) {
            const int nrow0 = row0 + BM;
            #pragma unroll
            for (int i = 0; i < 2; ++i) {
                const int c  = tid + i * 512;
                const int r  = c >> 4;
                const int c8 = c & 15;
                const float* src = (c8 < 12) ? (state  + (size_t)(nrow0 + r) * SDIM + c8 * 8)
                                             : (action + (size_t)(nrow0 + r) * ADIM + (c8 - 12) * 8);
                px[i][0] = ((const float4*)src)[0];
                px[i][1] = ((const float4*)src)[1];
            }
        }

        // ---- GEMM1 (transposed): D1[n][m] = W1 . x^T over this wave's 32 n ----
        // A = w1f (regs), B = xs rows: B[k=q*8+j][m'=ln] = x[mt*16+ln][ks*32+q*8+j]
        f32x4 acc[4][2];   // [mt][nt]
        #pragma unroll
        for (int mt = 0; mt < 4; ++mt)
            #pragma unroll
            for (int nt = 0; nt < 2; ++nt)
                acc[mt][nt] = (f32x4){0.f, 0.f, 0.f, 0.f};

        #pragma unroll
        for (int ks = 0; ks < 4; ++ks) {
            const int k0 = ks * 32 + q * 8;
            bf16x8 bfr[4];
            #pragma unroll
            for (int mt = 0; mt < 4; ++mt)
                bfr[mt] = *(const bf16x8*)&xs[(mt * 16 + ln) * XS_PITCH + k0];
            #pragma unroll
            for (int mt = 0; mt < 4; ++mt)
                #pragma unroll
                for (int nt = 0; nt < 2; ++nt)
                    acc[mt][nt] = __builtin_amdgcn_mfma_f32_16x16x32_bf16(w1f[ks][nt], bfr[mt], acc[mt][nt], 0, 0, 0);
        }

        // epi1: bias+relu; regs r=0..3 are 4 CONSECUTIVE hidden cols at batch
        // row mt*16+ln -> one ds_write_b64 per (nt,mt)
        #pragma unroll
        for (int nt = 0; nt < 2; ++nt) {
            #pragma unroll
            for (int mt = 0; mt < 4; ++mt) {
                bf16x4 v4;
                #pragma unroll
                for (int r = 0; r < 4; ++r) {
                    float v = acc[mt][nt][r] + b1v[nt][r];
                    v = v > 0.f ? v : 0.f;
                    v4[r] = (bf16)v;
                }
                *(bf16x4*)&h1s[(mt * 16 + ln) * H1_PITCH + colw + nt * 16 + q * 4] = v4;
            }
        }
        __syncthreads();

        // ---- GEMM2 (transposed): D2[n][m] = W2 . h1^T ----
        #pragma unroll
        for (int mt = 0; mt < 4; ++mt)
            #pragma unroll
            for (int nt = 0; nt < 2; ++nt)
                acc[mt][nt] = (f32x4){0.f, 0.f, 0.f, 0.f};

        #pragma unroll
        for (int ks = 0; ks < 8; ++ks) {
            const int k0 = ks * 32 + q * 8;
            bf16x8 bfr[4];
            #pragma unroll
            for (int mt = 0; mt < 4; ++mt)
                bfr[mt] = *(const bf16x8*)&h1s[(mt * 16 + ln) * H1_PITCH + k0];
            #pragma unroll
            for (int mt = 0; mt < 4; ++mt)
                #pragma unroll
                for (int nt = 0; nt < 2; ++nt)
                    acc[mt][nt] = __builtin_amdgcn_mfma_f32_16x16x32_bf16(w2f[ks][nt], bfr[mt], acc[mt][nt], 0, 0, 0);
        }

        // epi2: bias+relu+Wc-dot IN-LANE over (nt,r); per-lane partial[mt] is
        // the contribution of hidden cols {colw+nt*16+q*4+r} to batch row
        // mt*16+ln. Cross-lane reduce only over q: shfl_xor 16,32.
        float partial[4];
        #pragma unroll
        for (int mt = 0; mt < 4; ++mt) {
            float p = 0.f;
            #pragma unroll
            for (int nt = 0; nt < 2; ++nt)
                #pragma unroll
                for (int r = 0; r < 4; ++r) {
                    float v = acc[mt][nt][r] + b2v[nt][r];
                    v = v > 0.f ? v : 0.f;
                    p += v * wcv[nt][r];
                }
            partial[mt] = p;
        }
        #pragma unroll
        for (int mt = 0; mt < 4; ++mt) {
            partial[mt] += __shfl_xor(partial[mt], 16, 64);
            partial[mt] += __shfl_xor(partial[mt], 32, 64);
        }
        if (q == 0) {
            #pragma unroll
            for (int mt = 0; mt < 4; ++mt)
                sPart[wave][mt * 16 + ln] = partial[mt];
        }
        __syncthreads();

        if (tid < BM) {
            float v = bc;
            #pragma unroll
            for (int w = 0; w < 8; ++w) v += sPart[w][tid];
            out[row0 + tid] = v;
        }
        // barrier above also orders next tile's xs writes after this tile's reads
    }
}

extern "C" void kernel_launch(void* const* d_in, const int* in_sizes, int n_in,
                              void* d_out, int out_size, void* d_ws, size_t ws_size,
                              hipStream_t stream) {
    const float* state  = (const float*)d_in[0];
    const float* action = (const float*)d_in[1];
    const float* alphas = (const float*)d_in[2];
    const float* W1     = (const float*)d_in[3];
    const float* b1     = (const float*)d_in[4];
    const float* W2     = (const float*)d_in[5];
    const float* b2     = (const float*)d_in[6];
    const float* Wh     = (const float*)d_in[7];
    const float* bh     = (const float*)d_in[8];
    float* out = (float*)d_out;

    bf16*  W1bf = (bf16*)d_ws;                                  // 65536 B
    bf16*  W2bf = (bf16*)((char*)d_ws + 65536);                 // 131072 B
    float* Wc   = (float*)((char*)d_ws + 65536 + 131072);       // 257 * 4 B

    prep_kernel<<<256, 256, 0, stream>>>(W1, W2, alphas, Wh, bh, W1bf, W2bf, Wc);
    critic_kernel<<<B_TOTAL / (BM * NTILES), 512, 0, stream>>>(state, action, b1, b2, W1bf, W2bf, Wc, out);
}

// Round 5
// 118.638 us; speedup vs baseline: 1.3185x; 1.2442x over previous
//
#include <hip/hip_runtime.h>
#include <hip/hip_bf16.h>

// CriticREM: out = relu(relu([state|action]W1^T+b1)W2^T+b2) @ Wc^T + bc
//   Wc = sum_h alpha_h * Wh[h], bc = sum_h alpha_h * bh[h]
// B=65536, IN=128, HID=256, NUM_HEADS=200, OUT=1
//
// R10 (2nd resubmit; R3+R4 benches were GPUAcquisitionTimeout — no data):
//   R9 with the launch_bounds regression fixed — (512,2), grid 512.
//   R9 evidence: __launch_bounds__(512,4) is CUDA-semantics min-BLOCKS/CU
//   -> compiler capped VGPR at 64 (was 128) -> register-resident weights
//   spilled to scratch: WRITE_SIZE 256KB->87MB, FETCH 19->84MB, critic
//   60-68us. The occupancy experiment was never run.
//   (512,2) = 2 blocks/CU min = 4 waves/SIMD -> VGPR cap 128 = exactly
//   what the kernel needs (R7/R8 measured 128, no spills). Grid 512
//   (NTILES=2) then gives 2 co-resident blocks/CU: interleaved barrier
//   convoys, one block's compute hides the other's stalls.
//   Main GEMM loop byte-identical to R7/R8/R9.

#define B_TOTAL 65536
#define SDIM 96
#define ADIM 32
#define IN_F 128
#define HID 256
#define NHEADS 200
#define BM 64           // batch rows per tile
#define NTILES 2        // tiles per block (grid 512 -> 2 blocks/CU)
#define XS_PITCH 132    // 264B row stride = 66 dw == 2 mod 32: conflict-free class
#define H1_PITCH 260    // 520B row stride = 130 dw == 2 mod 32: measured 0 (R2)

typedef __bf16 bf16;
typedef __attribute__((ext_vector_type(4))) __bf16 bf16x4;
typedef __attribute__((ext_vector_type(8))) __bf16 bf16x8;
typedef __attribute__((ext_vector_type(4))) float f32x4;

// ---- prep: W1,W2 -> bf16 in ws; collapse heads: Wc[256], bc (fp32) ----
__global__ void prep_kernel(const float* __restrict__ W1, const float* __restrict__ W2,
                            const float* __restrict__ alphas, const float* __restrict__ Wh,
                            const float* __restrict__ bh,
                            bf16* __restrict__ W1bf, bf16* __restrict__ W2bf,
                            float* __restrict__ Wc) {
    int tid = blockIdx.x * blockDim.x + threadIdx.x;
    if (tid < IN_F * HID) W1bf[tid] = (bf16)W1[tid];
    if (tid < HID * HID)  W2bf[tid] = (bf16)W2[tid];
    if (tid < HID) {
        float acc = 0.f;
        #pragma unroll 8
        for (int h = 0; h < NHEADS; ++h) acc += alphas[h] * Wh[h * HID + tid];
        Wc[tid] = acc;
    }
    if (tid == HID) {
        float acc = 0.f;
        for (int h = 0; h < NHEADS; ++h) acc += alphas[h] * bh[h];
        Wc[HID] = acc;   // bc
    }
}

// ---- main fused kernel: 512 threads (8 waves), 2 tiles, 2 blocks/CU ----
__global__ __launch_bounds__(512, 2) void critic_kernel(
        const float* __restrict__ state, const float* __restrict__ action,
        const float* __restrict__ b1, const float* __restrict__ b2,
        const bf16* __restrict__ W1bf, const bf16* __restrict__ W2bf,
        const float* __restrict__ Wc, float* __restrict__ out) {

    __shared__ bf16 xs[BM * XS_PITCH];     // 16896 B, x tile [batch][k]
    __shared__ bf16 h1s[BM * H1_PITCH];    // 33280 B, h1 tile [batch][hidden]
    __shared__ float sPart[8][BM];         // 2048 B

    const int tid  = threadIdx.x;
    const int wave = tid >> 6;      // 0..7
    const int lane = tid & 63;
    const int q    = lane >> 4;     // 0..3
    const int ln   = lane & 15;     // 0..15
    const int colw = wave * 32;     // this wave's 32-hidden-col slice
    const int brow0 = blockIdx.x * (BM * NTILES);

    // ---- x prefetch for tile 0 FIRST: HBM stream, longest latency ----
    float4 px[2][2];
    #pragma unroll
    for (int i = 0; i < 2; ++i) {
        const int c  = tid + i * 512;
        const int r  = c >> 4;
        const int c8 = c & 15;
        const float* src = (c8 < 12) ? (state  + (size_t)(brow0 + r) * SDIM + c8 * 8)
                                     : (action + (size_t)(brow0 + r) * ADIM + (c8 - 12) * 8);
        px[i][0] = ((const float4*)src)[0];
        px[i][1] = ((const float4*)src)[1];
    }

    // ---- preamble: ALL weight fragments into registers, once per block ----
    // A-operand layout: A[m'=ln][k=q*8+j] -> same data we always loaded.
    bf16x8 w1f[4][2];   // 32 VGPR : W1[colw+nt*16+ln][ks*32+q*8 ..]
    #pragma unroll
    for (int ks = 0; ks < 4; ++ks)
        #pragma unroll
        for (int nt = 0; nt < 2; ++nt)
            w1f[ks][nt] = *(const bf16x8*)&W1bf[(size_t)(colw + nt * 16 + ln) * IN_F + ks * 32 + q * 8];

    bf16x8 w2f[8][2];   // 64 VGPR
    #pragma unroll
    for (int ks = 0; ks < 8; ++ks)
        #pragma unroll
        for (int nt = 0; nt < 2; ++nt)
            w2f[ks][nt] = *(const bf16x8*)&W2bf[(size_t)(colw + nt * 16 + ln) * HID + ks * 32 + q * 8];

    // epilogue constants: hidden col n = colw + nt*16 + q*4 + r  -> float4 loads
    f32x4 b1v[2], b2v[2], wcv[2];
    #pragma unroll
    for (int nt = 0; nt < 2; ++nt) {
        const int n4 = colw + nt * 16 + q * 4;
        b1v[nt] = *(const f32x4*)&b1[n4];
        b2v[nt] = *(const f32x4*)&b2[n4];
        wcv[nt] = *(const f32x4*)&Wc[n4];
    }
    const float bc = Wc[HID];

    for (int t = 0; t < NTILES; ++t) {
        const int row0 = brow0 + t * BM;

        // stage x tile: fp32 -> bf16 into LDS [batch][k]
        #pragma unroll
        for (int i = 0; i < 2; ++i) {
            const int c  = tid + i * 512;
            const int r  = c >> 4;
            const int c8 = c & 15;
            bf16x8 v = (bf16x8){(bf16)px[i][0].x, (bf16)px[i][0].y, (bf16)px[i][0].z, (bf16)px[i][0].w,
                                (bf16)px[i][1].x, (bf16)px[i][1].y, (bf16)px[i][1].z, (bf16)px[i][1].w};
            *(bf16x8*)&xs[r * XS_PITCH + c8 * 8] = v;
        }
        __syncthreads();

        // prefetch NEXT tile's x while this tile computes
        if (t + 1 < NTILES) {
            const int nrow0 = row0 + BM;
            #pragma unroll
            for (int i = 0; i < 2; ++i) {
                const int c  = tid + i * 512;
                const int r  = c >> 4;
                const int c8 = c & 15;
                const float* src = (c8 < 12) ? (state  + (size_t)(nrow0 + r) * SDIM + c8 * 8)
                                             : (action + (size_t)(nrow0 + r) * ADIM + (c8 - 12) * 8);
                px[i][0] = ((const float4*)src)[0];
                px[i][1] = ((const float4*)src)[1];
            }
        }

        // ---- GEMM1 (transposed): D1[n][m] = W1 . x^T over this wave's 32 n ----
        // A = w1f (regs), B = xs rows: B[k=q*8+j][m'=ln] = x[mt*16+ln][ks*32+q*8+j]
        f32x4 acc[4][2];   // [mt][nt]
        #pragma unroll
        for (int mt = 0; mt < 4; ++mt)
            #pragma unroll
            for (int nt = 0; nt < 2; ++nt)
                acc[mt][nt] = (f32x4){0.f, 0.f, 0.f, 0.f};

        #pragma unroll
        for (int ks = 0; ks < 4; ++ks) {
            const int k0 = ks * 32 + q * 8;
            bf16x8 bfr[4];
            #pragma unroll
            for (int mt = 0; mt < 4; ++mt)
                bfr[mt] = *(const bf16x8*)&xs[(mt * 16 + ln) * XS_PITCH + k0];
            #pragma unroll
            for (int mt = 0; mt < 4; ++mt)
                #pragma unroll
                for (int nt = 0; nt < 2; ++nt)
                    acc[mt][nt] = __builtin_amdgcn_mfma_f32_16x16x32_bf16(w1f[ks][nt], bfr[mt], acc[mt][nt], 0, 0, 0);
        }

        // epi1: bias+relu; regs r=0..3 are 4 CONSECUTIVE hidden cols at batch
        // row mt*16+ln -> one ds_write_b64 per (nt,mt)
        #pragma unroll
        for (int nt = 0; nt < 2; ++nt) {
            #pragma unroll
            for (int mt = 0; mt < 4; ++mt) {
                bf16x4 v4;
                #pragma unroll
                for (int r = 0; r < 4; ++r) {
                    float v = acc[mt][nt][r] + b1v[nt][r];
                    v = v > 0.f ? v : 0.f;
                    v4[r] = (bf16)v;
                }
                *(bf16x4*)&h1s[(mt * 16 + ln) * H1_PITCH + colw + nt * 16 + q * 4] = v4;
            }
        }
        __syncthreads();

        // ---- GEMM2 (transposed): D2[n][m] = W2 . h1^T ----
        #pragma unroll
        for (int mt = 0; mt < 4; ++mt)
            #pragma unroll
            for (int nt = 0; nt < 2; ++nt)
                acc[mt][nt] = (f32x4){0.f, 0.f, 0.f, 0.f};

        #pragma unroll
        for (int ks = 0; ks < 8; ++ks) {
            const int k0 = ks * 32 + q * 8;
            bf16x8 bfr[4];
            #pragma unroll
            for (int mt = 0; mt < 4; ++mt)
                bfr[mt] = *(const bf16x8*)&h1s[(mt * 16 + ln) * H1_PITCH + k0];
            #pragma unroll
            for (int mt = 0; mt < 4; ++mt)
                #pragma unroll
                for (int nt = 0; nt < 2; ++nt)
                    acc[mt][nt] = __builtin_amdgcn_mfma_f32_16x16x32_bf16(w2f[ks][nt], bfr[mt], acc[mt][nt], 0, 0, 0);
        }

        // epi2: bias+relu+Wc-dot IN-LANE over (nt,r); per-lane partial[mt] is
        // the contribution of hidden cols {colw+nt*16+q*4+r} to batch row
        // mt*16+ln. Cross-lane reduce only over q: shfl_xor 16,32.
        float partial[4];
        #pragma unroll
        for (int mt = 0; mt < 4; ++mt) {
            float p = 0.f;
            #pragma unroll
            for (int nt = 0; nt < 2; ++nt)
                #pragma unroll
                for (int r = 0; r < 4; ++r) {
                    float v = acc[mt][nt][r] + b2v[nt][r];
                    v = v > 0.f ? v : 0.f;
                    p += v * wcv[nt][r];
                }
            partial[mt] = p;
        }
        #pragma unroll
        for (int mt = 0; mt < 4; ++mt) {
            partial[mt] += __shfl_xor(partial[mt], 16, 64);
            partial[mt] += __shfl_xor(partial[mt], 32, 64);
        }
        if (q == 0) {
            #pragma unroll
            for (int mt = 0; mt < 4; ++mt)
                sPart[wave][mt * 16 + ln] = partial[mt];
        }
        __syncthreads();

        if (tid < BM) {
            float v = bc;
            #pragma unroll
            for (int w = 0; w < 8; ++w) v += sPart[w][tid];
            out[row0 + tid] = v;
        }
        // barrier above also orders next tile's xs writes after this tile's reads
    }
}

extern "C" void kernel_launch(void* const* d_in, const int* in_sizes, int n_in,
                              void* d_out, int out_size, void* d_ws, size_t ws_size,
                              hipStream_t stream) {
    const float* state  = (const float*)d_in[0];
    const float* action = (const float*)d_in[1];
    const float* alphas = (const float*)d_in[2];
    const float* W1     = (const float*)d_in[3];
    const float* b1     = (const float*)d_in[4];
    const float* W2     = (const float*)d_in[5];
    const float* b2     = (const float*)d_in[6];
    const float* Wh     = (const float*)d_in[7];
    const float* bh     = (const float*)d_in[8];
    float* out = (float*)d_out;

    bf16*  W1bf = (bf16*)d_ws;                                  // 65536 B
    bf16*  W2bf = (bf16*)((char*)d_ws + 65536);                 // 131072 B
    float* Wc   = (float*)((char*)d_ws + 65536 + 131072);       // 257 * 4 B

    prep_kernel<<<256, 256, 0, stream>>>(W1, W2, alphas, Wh, bh, W1bf, W2bf, Wc);
    critic_kernel<<<B_TOTAL / (BM * NTILES), 512, 0, stream>>>(state, action, b1, b2, W1bf, W2bf, Wc, out);
}

// Round 10
// 110.694 us; speedup vs baseline: 1.4132x; 1.0718x over previous
//
#include <hip/hip_runtime.h>
#include <hip/hip_bf16.h>

// CriticREM: out = relu(relu([state|action]W1^T+b1)W2^T+b2) @ Wc^T + bc
//   Wc = sum_h alpha_h * Wh[h], bc = sum_h alpha_h * bh[h]
// B=65536, IN=128, HID=256, NUM_HEADS=200, OUT=1
//
// R11 (5th resubmit; R6-R9 benches were GPUAcquisitionTimeout — no data):
//   NO WORKSPACE + CHEAP in-kernel prep (the experiment R8 botched).
//   Cross-round accounting: R8 (no-ws, critic=94) residual 62us fits at
//   most ONE 44us ws-poison fill; R9 (ws, critic=61) residual 87us needs
//   TWO. => using d_ws adds ~44us of poison-fill to the timed window.
//   R8 lost anyway because its head-collapse was serial+16x-redundant
//   (~55us/block). This version keeps R7's best config (grid 256,
//   NTILES=4, (512,2)) and does prep cheaply inside critic:
//     - Wc: cooperative, 512 threads: (half,j)=(tid>>8,tid&255) sums 100
//       heads of alphas[h]*Wh[h][j] (coalesced, L2-resident) into LDS;
//       combine halves after barrier. ~3-6us.
//     - bc: wave 0 lane-strided + shfl_xor reduce.
//     - W1/W2 frags: fp32 direct + in-register bf16 cast (bit-identical
//       to prep_kernel's conversion).
//   Main GEMM loop byte-identical to R7.

#define B_TOTAL 65536
#define SDIM 96
#define ADIM 32
#define IN_F 128
#define HID 256
#define NHEADS 200
#define BM 64           // batch rows per tile
#define NTILES 4        // tiles per block (grid 256)
#define XS_PITCH 132    // 264B row stride = 66 dw == 2 mod 32: conflict-free class
#define H1_PITCH 260    // 520B row stride = 130 dw == 2 mod 32: measured 0 (R2)

typedef __bf16 bf16;
typedef __attribute__((ext_vector_type(4))) __bf16 bf16x4;
typedef __attribute__((ext_vector_type(8))) __bf16 bf16x8;
typedef __attribute__((ext_vector_type(4))) float f32x4;

// ---- single fused kernel: 512 threads (8 waves), persistent over 4 tiles ----
__global__ __launch_bounds__(512, 2) void critic_kernel(
        const float* __restrict__ state, const float* __restrict__ action,
        const float* __restrict__ alphas,
        const float* __restrict__ W1, const float* __restrict__ b1,
        const float* __restrict__ W2, const float* __restrict__ b2,
        const float* __restrict__ Wh, const float* __restrict__ bh,
        float* __restrict__ out) {

    __shared__ bf16 xs[BM * XS_PITCH];     // 16896 B, x tile [batch][k]
    __shared__ bf16 h1s[BM * H1_PITCH];    // 33280 B, h1 tile [batch][hidden]
    __shared__ float sPart[8][BM];         // 2048 B
    __shared__ float wcs[2][HID];          // 2048 B, head-collapse halves
    __shared__ float bcs;

    const int tid  = threadIdx.x;
    const int wave = tid >> 6;      // 0..7
    const int lane = tid & 63;
    const int q    = lane >> 4;     // 0..3
    const int ln   = lane & 15;     // 0..15
    const int colw = wave * 32;     // this wave's 32-hidden-col slice
    const int brow0 = blockIdx.x * (BM * NTILES);

    // ---- x prefetch for tile 0 FIRST: HBM stream, longest latency ----
    float4 px[2][2];
    #pragma unroll
    for (int i = 0; i < 2; ++i) {
        const int c  = tid + i * 512;
        const int r  = c >> 4;
        const int c8 = c & 15;
        const float* src = (c8 < 12) ? (state  + (size_t)(brow0 + r) * SDIM + c8 * 8)
                                     : (action + (size_t)(brow0 + r) * ADIM + (c8 - 12) * 8);
        px[i][0] = ((const float4*)src)[0];
        px[i][1] = ((const float4*)src)[1];
    }

    // ---- cheap in-kernel prep: head collapse, cooperative over 512 thr ----
    // thread (half=tid>>8, j=tid&255) sums heads [half*100, half*100+100)
    // of alphas[h]*Wh[h][j]; Wh reads coalesced (consecutive j), L2-resident.
    {
        const int j    = tid & 255;
        const int half = tid >> 8;
        const int h0   = half * 100;
        float a = 0.f;
        #pragma unroll 10
        for (int hh = 0; hh < 100; ++hh) {
            const int h = h0 + hh;
            a += alphas[h] * Wh[(size_t)h * HID + j];
        }
        wcs[half][j] = a;
    }
    if (tid < 64) {   // wave 0: bc = sum_h alphas[h]*bh[h]
        float p = 0.f;
        for (int h = tid; h < NHEADS; h += 64) p += alphas[h] * bh[h];
        #pragma unroll
        for (int s = 1; s < 64; s <<= 1) p += __shfl_xor(p, s, 64);
        if (tid == 0) bcs = p;
    }

    // ---- preamble: ALL weight fragments into registers, once per block ----
    // A-operand layout: A[m'=ln][k=q*8+j]; fp32 source, cast in-register
    // (bit-identical to prep_kernel's (bf16) conversion).
    bf16x8 w1f[4][2];   // 32 VGPR : W1[colw+nt*16+ln][ks*32+q*8 ..]
    #pragma unroll
    for (int ks = 0; ks < 4; ++ks)
        #pragma unroll
        for (int nt = 0; nt < 2; ++nt) {
            const float* p = &W1[(size_t)(colw + nt * 16 + ln) * IN_F + ks * 32 + q * 8];
            float4 lo = ((const float4*)p)[0];
            float4 hi = ((const float4*)p)[1];
            w1f[ks][nt] = (bf16x8){(bf16)lo.x, (bf16)lo.y, (bf16)lo.z, (bf16)lo.w,
                                   (bf16)hi.x, (bf16)hi.y, (bf16)hi.z, (bf16)hi.w};
        }

    bf16x8 w2f[8][2];   // 64 VGPR
    #pragma unroll
    for (int ks = 0; ks < 8; ++ks)
        #pragma unroll
        for (int nt = 0; nt < 2; ++nt) {
            const float* p = &W2[(size_t)(colw + nt * 16 + ln) * HID + ks * 32 + q * 8];
            float4 lo = ((const float4*)p)[0];
            float4 hi = ((const float4*)p)[1];
            w2f[ks][nt] = (bf16x8){(bf16)lo.x, (bf16)lo.y, (bf16)lo.z, (bf16)lo.w,
                                   (bf16)hi.x, (bf16)hi.y, (bf16)hi.z, (bf16)hi.w};
        }

    // epilogue constants: hidden col n = colw + nt*16 + q*4 + r -> float4 loads
    f32x4 b1v[2], b2v[2], wcv[2];
    #pragma unroll
    for (int nt = 0; nt < 2; ++nt) {
        const int n4 = colw + nt * 16 + q * 4;
        b1v[nt] = *(const f32x4*)&b1[n4];
        b2v[nt] = *(const f32x4*)&b2[n4];
    }
    __syncthreads();   // wcs/bcs ready
    #pragma unroll
    for (int nt = 0; nt < 2; ++nt) {
        const int n4 = colw + nt * 16 + q * 4;
        const f32x4 w0 = *(const f32x4*)&wcs[0][n4];
        const f32x4 w1v = *(const f32x4*)&wcs[1][n4];
        #pragma unroll
        for (int r = 0; r < 4; ++r) wcv[nt][r] = w0[r] + w1v[r];
    }
    const float bc = bcs;

    for (int t = 0; t < NTILES; ++t) {
        const int row0 = brow0 + t * BM;

        // stage x tile: fp32 -> bf16 into LDS [batch][k]
        #pragma unroll
        for (int i = 0; i < 2; ++i) {
            const int c  = tid + i * 512;
            const int r  = c >> 4;
            const int c8 = c & 15;
            bf16x8 v = (bf16x8){(bf16)px[i][0].x, (bf16)px[i][0].y, (bf16)px[i][0].z, (bf16)px[i][0].w,
                                (bf16)px[i][1].x, (bf16)px[i][1].y, (bf16)px[i][1].z, (bf16)px[i][1].w};
            *(bf16x8*)&xs[r * XS_PITCH + c8 * 8] = v;
        }
        __syncthreads();

        // prefetch NEXT tile's x while this tile computes
        if (t + 1 < NTILES) {
            const int nrow0 = row0 + BM;
            #pragma unroll
            for (int i = 0; i < 2; ++i) {
                const int c  = tid + i * 512;
                const int r  = c >> 4;
                const int c8 = c & 15;
                const float* src = (c8 < 12) ? (state  + (size_t)(nrow0 + r) * SDIM + c8 * 8)
                                             : (action + (size_t)(nrow0 + r) * ADIM + (c8 - 12) * 8);
                px[i][0] = ((const float4*)src)[0];
                px[i][1] = ((const float4*)src)[1];
            }
        }

        // ---- GEMM1 (transposed): D1[n][m] = W1 . x^T over this wave's 32 n ----
        // A = w1f (regs), B = xs rows: B[k=q*8+j][m'=ln] = x[mt*16+ln][ks*32+q*8+j]
        f32x4 acc[4][2];   // [mt][nt]
        #pragma unroll
        for (int mt = 0; mt < 4; ++mt)
            #pragma unroll
            for (int nt = 0; nt < 2; ++nt)
                acc[mt][nt] = (f32x4){0.f, 0.f, 0.f, 0.f};

        #pragma unroll
        for (int ks = 0; ks < 4; ++ks) {
            const int k0 = ks * 32 + q * 8;
            bf16x8 bfr[4];
            #pragma unroll
            for (int mt = 0; mt < 4; ++mt)
                bfr[mt] = *(const bf16x8*)&xs[(mt * 16 + ln) * XS_PITCH + k0];
            #pragma unroll
            for (int mt = 0; mt < 4; ++mt)
                #pragma unroll
                for (int nt = 0; nt < 2; ++nt)
                    acc[mt][nt] = __builtin_amdgcn_mfma_f32_16x16x32_bf16(w1f[ks][nt], bfr[mt], acc[mt][nt], 0, 0, 0);
        }

        // epi1: bias+relu; regs r=0..3 are 4 CONSECUTIVE hidden cols at batch
        // row mt*16+ln -> one ds_write_b64 per (nt,mt)
        #pragma unroll
        for (int nt = 0; nt < 2; ++nt) {
            #pragma unroll
            for (int mt = 0; mt < 4; ++mt) {
                bf16x4 v4;
                #pragma unroll
                for (int r = 0; r < 4; ++r) {
                    float v = acc[mt][nt][r] + b1v[nt][r];
                    v = v > 0.f ? v : 0.f;
                    v4[r] = (bf16)v;
                }
                *(bf16x4*)&h1s[(mt * 16 + ln) * H1_PITCH + colw + nt * 16 + q * 4] = v4;
            }
        }
        __syncthreads();

        // ---- GEMM2 (transposed): D2[n][m] = W2 . h1^T ----
        #pragma unroll
        for (int mt = 0; mt < 4; ++mt)
            #pragma unroll
            for (int nt = 0; nt < 2; ++nt)
                acc[mt][nt] = (f32x4){0.f, 0.f, 0.f, 0.f};

        #pragma unroll
        for (int ks = 0; ks < 8; ++ks) {
            const int k0 = ks * 32 + q * 8;
            bf16x8 bfr[4];
            #pragma unroll
            for (int mt = 0; mt < 4; ++mt)
                bfr[mt] = *(const bf16x8*)&h1s[(mt * 16 + ln) * H1_PITCH + k0];
            #pragma unroll
            for (int mt = 0; mt < 4; ++mt)
                #pragma unroll
                for (int nt = 0; nt < 2; ++nt)
                    acc[mt][nt] = __builtin_amdgcn_mfma_f32_16x16x32_bf16(w2f[ks][nt], bfr[mt], acc[mt][nt], 0, 0, 0);
        }

        // epi2: bias+relu+Wc-dot IN-LANE over (nt,r); per-lane partial[mt] is
        // the contribution of hidden cols {colw+nt*16+q*4+r} to batch row
        // mt*16+ln. Cross-lane reduce only over q: shfl_xor 16,32.
        float partial[4];
        #pragma unroll
        for (int mt = 0; mt < 4; ++mt) {
            float p = 0.f;
            #pragma unroll
            for (int nt = 0; nt < 2; ++nt)
                #pragma unroll
                for (int r = 0; r < 4; ++r) {
                    float v = acc[mt][nt][r] + b2v[nt][r];
                    v = v > 0.f ? v : 0.f;
                    p += v * wcv[nt][r];
                }
            partial[mt] = p;
        }
        #pragma unroll
        for (int mt = 0; mt < 4; ++mt) {
            partial[mt] += __shfl_xor(partial[mt], 16, 64);
            partial[mt] += __shfl_xor(partial[mt], 32, 64);
        }
        if (q == 0) {
            #pragma unroll
            for (int mt = 0; mt < 4; ++mt)
                sPart[wave][mt * 16 + ln] = partial[mt];
        }
        __syncthreads();

        if (tid < BM) {
            float v = bc;
            #pragma unroll
            for (int w = 0; w < 8; ++w) v += sPart[w][tid];
            out[row0 + tid] = v;
        }
        // barrier above also orders next tile's xs writes after this tile's reads
    }
}

extern "C" void kernel_launch(void* const* d_in, const int* in_sizes, int n_in,
                              void* d_out, int out_size, void* d_ws, size_t ws_size,
                              hipStream_t stream) {
    const float* state  = (const float*)d_in[0];
    const float* action = (const float*)d_in[1];
    const float* alphas = (const float*)d_in[2];
    const float* W1     = (const float*)d_in[3];
    const float* b1     = (const float*)d_in[4];
    const float* W2     = (const float*)d_in[5];
    const float* b2     = (const float*)d_in[6];
    const float* Wh     = (const float*)d_in[7];
    const float* bh     = (const float*)d_in[8];
    float* out = (float*)d_out;

    // d_ws deliberately UNUSED (R11): ws usage adds a ~44us 256MiB poison
    // fill to the timed window (R8 vs R9 residual accounting).
    (void)d_ws; (void)ws_size;

    critic_kernel<<<B_TOTAL / (BM * NTILES), 512, 0, stream>>>(
        state, action, alphas, W1, b1, W2, b2, Wh, bh, out);
}